// Round 2
// 402.108 us; speedup vs baseline: 1.1715x; 1.1715x over previous
//
#include <hip/hip_runtime.h>
#include <math.h>

// TriangleAttention (starting node): B=1, S=384, CZ=128, H=4, CH=32.
// I/O is fp32 (reference dtype); internal compute bf16 MFMA + fp32 softmax/LN.
// Pair bias (Wb) broadcasts along the softmax (key) axis -> softmax-invariant -> skipped.
// MFMA 16x16x32 bf16 layouts (verified m89/m91):
//   A: lane holds A[m=lane&15][k=(lane>>4)*8 + j], j=0..7
//   B: lane holds B[k=(lane>>4)*8 + j][n=lane&15]
//   C/D: col = lane&15, row = (lane>>4)*4 + reg

typedef unsigned short u16;
typedef __attribute__((ext_vector_type(8))) short short8;
typedef __attribute__((ext_vector_type(4))) float float4v;

union U8 { short8 s; u16 h[8]; };

__device__ __forceinline__ float bf2f(u16 x){
    unsigned v = ((unsigned)x) << 16;
    float f; __builtin_memcpy(&f, &v, 4);
    return f;
}
__device__ __forceinline__ u16 f2bf(float f){
    unsigned v; __builtin_memcpy(&v, &f, 4);
    unsigned r = (v + 0x7FFFu + ((v >> 16) & 1u)) >> 16;  // RNE
    return (u16)r;
}
__device__ __forceinline__ short8 pack8f(const float* p){
    const float4 a = ((const float4*)p)[0];
    const float4 b = ((const float4*)p)[1];
    U8 u;
    u.h[0]=f2bf(a.x); u.h[1]=f2bf(a.y); u.h[2]=f2bf(a.z); u.h[3]=f2bf(a.w);
    u.h[4]=f2bf(b.x); u.h[5]=f2bf(b.y); u.h[6]=f2bf(b.z); u.h[7]=f2bf(b.w);
    return u.s;
}

// ---------------------------------------------------------------------------
// Kernel 1: LayerNorm + fused projection GEMM [64 rows x 320 cols], K=128.
// grid 2304 x 256 threads. Wave w handles n-tiles w*5..w*5+4 over all 64 rows.
// Outputs bf16: Q (scaled by 1/sqrt(32)), K|V packed, G = sigmoid(zn@Wg^T+bg).
// ---------------------------------------------------------------------------
__global__ __launch_bounds__(256) void k1_ln_proj(
    const float* __restrict__ z, const float* __restrict__ lnw, const float* __restrict__ lnb,
    const float* __restrict__ Wq, const float* __restrict__ Wk, const float* __restrict__ Wv,
    const float* __restrict__ Wg, const float* __restrict__ bg,
    u16* __restrict__ Qbuf, u16* __restrict__ KVbuf, u16* __restrict__ Gbuf)
{
    __shared__ __align__(16) u16 zn[64][136];   // +8 pad
    const int tid = threadIdx.x;
    const long rowg0 = (long)blockIdx.x * 64;

    {   // LayerNorm: 4 threads per row, 32 elems each, fp32 stats
        const int r = tid >> 2, p = tid & 3;
        const float* src = z + (rowg0 + r) * 128 + p * 32;
        float x[32];
        #pragma unroll
        for (int q = 0; q < 8; q++){
            const float4 v = ((const float4*)src)[q];
            x[q*4+0]=v.x; x[q*4+1]=v.y; x[q*4+2]=v.z; x[q*4+3]=v.w;
        }
        float s = 0.f, ss = 0.f;
        #pragma unroll
        for (int t = 0; t < 32; t++){ s += x[t]; ss += x[t]*x[t]; }
        s += __shfl_xor(s, 1);  ss += __shfl_xor(ss, 1);
        s += __shfl_xor(s, 2);  ss += __shfl_xor(ss, 2);
        const float mean = s * (1.f/128.f);
        const float var  = ss * (1.f/128.f) - mean*mean;
        const float rstd = rsqrtf(var + 1e-5f);
        #pragma unroll
        for (int t = 0; t < 32; t++){
            const int c = p*32 + t;
            zn[r][c] = f2bf((x[t]-mean)*rstd*lnw[c] + lnb[c]);
        }
    }
    __syncthreads();

    const int lane = tid & 63, wave = tid >> 6;
    const int l15 = lane & 15, quad = lane >> 4;

    short8 A[4][4];                       // 4 m-tiles x 4 k-steps, cached in regs
    #pragma unroll
    for (int m = 0; m < 4; m++)
        #pragma unroll
        for (int ks = 0; ks < 4; ks++)
            A[m][ks] = *(const short8*)&zn[m*16 + l15][ks*32 + quad*8];

    #pragma unroll
    for (int g = 0; g < 5; g++){
        const int nt = wave*5 + g;        // 0..19 : q(0-7) k(8-9) v(10-11) g(12-19)
        const float* Wp; int nbase, kind;
        if (nt < 8)       { Wp = Wq; nbase = nt*16;      kind = 0; }
        else if (nt < 10) { Wp = Wk; nbase = (nt-8)*16;  kind = 1; }
        else if (nt < 12) { Wp = Wv; nbase = (nt-10)*16; kind = 2; }
        else              { Wp = Wg; nbase = (nt-12)*16; kind = 3; }
        const float* bp = Wp + (nbase + l15)*128 + quad*8;
        short8 B[4];
        #pragma unroll
        for (int ks = 0; ks < 4; ks++) B[ks] = pack8f(bp + ks*32);
        #pragma unroll
        for (int m = 0; m < 4; m++){
            float4v c = {0.f,0.f,0.f,0.f};
            #pragma unroll
            for (int ks = 0; ks < 4; ks++)
                c = __builtin_amdgcn_mfma_f32_16x16x32_bf16(A[m][ks], B[ks], c, 0, 0, 0);
            const int n = nt*16 + l15;
            #pragma unroll
            for (int r = 0; r < 4; r++){
                const long row = rowg0 + m*16 + quad*4 + r;
                const float v = c[r];
                if (kind == 0)      Qbuf[row*128 + n] = f2bf(v * 0.17677669529663689f); // 1/sqrt(32)
                else if (kind == 1) KVbuf[row*64 + (n - 128)] = f2bf(v);
                else if (kind == 2) KVbuf[row*64 + (n - 160) + 32] = f2bf(v);
                else {
                    const float gg = 1.f/(1.f + __expf(-(v + bg[n - 192])));
                    Gbuf[row*128 + (n - 192)] = f2bf(gg);
                }
            }
        }
    }
}

// ---------------------------------------------------------------------------
// Kernel 2: attention. One block per (i,h): 384 j-rows x 384 keys, CH=32.
// K,V^T staged in LDS; per-wave HALF-WIDTH P buffer (192 keys) so the C->A
// layout transform double-uses the same LDS: write kt 0..11, PV kk 0..5,
// then write kt 12..23, PV kk 6..11. Per-wave in-order LDS => no barrier.
// LDS total 81,408 B <= 81,920 -> 2 blocks/CU (was 105,984 -> 1 block/CU).
// Softmax normalization deferred to the epilogue (one inv-mult per output).
// O = g * (softmax(QK^T) V) written in-place over Q (strict read-before-write).
// ---------------------------------------------------------------------------
__global__ __launch_bounds__(256, 2) void k2_attn(
    const u16* __restrict__ KVbuf, const u16* __restrict__ Gbuf, u16* __restrict__ QObuf)
{
    __shared__ __align__(16) u16 Ks[384][40];      // K [key][c], +8 pad        30720 B
    __shared__ __align__(16) u16 Vt[32][392];      // V^T [c][key], +8 pad      25088 B
    __shared__ __align__(16) u16 Pb[4][16][200];   // per-wave P half-chunk     25600 B
    const int i = blockIdx.x >> 2, h = blockIdx.x & 3;
    const int tid = threadIdx.x;
    {
        const u16* kvsrc = KVbuf + (long)i * 384 * 64;
        for (int idx = tid; idx < 384*8; idx += 256){
            const int k = idx >> 3, c8 = idx & 7;
            U8 d; d.s = *(const short8*)(kvsrc + k*64 + c8*8);
            if (c8 < 4) *(short8*)&Ks[k][c8*8] = d.s;
            else {
                const int c0 = (c8 - 4) * 8;
                #pragma unroll
                for (int jj = 0; jj < 8; jj++) Vt[c0 + jj][k] = d.h[jj];
            }
        }
    }
    __syncthreads();

    const int lane = tid & 63, wave = tid >> 6;
    const int l15 = lane & 15, quad = lane >> 4;
    const u16* qbase = QObuf + (long)i * 384 * 128 + h * 32;
    const u16* gbase = Gbuf  + (long)i * 384 * 128 + h * 32;
    u16* obase = QObuf + (long)i * 384 * 128 + h * 32;

    for (int t = 0; t < 6; t++){
        const int j0 = (wave*6 + t) * 16;
        // Q fragment straight from global (16B/lane, reused for 24 MFMAs)
        const short8 aq = *(const short8*)(qbase + (long)(j0 + l15)*128 + quad*8);
        float4v acc[24];
        #pragma unroll
        for (int kt = 0; kt < 24; kt++){
            const short8 bk = *(const short8*)&Ks[kt*16 + l15][quad*8];
            float4v zero = {0.f,0.f,0.f,0.f};
            acc[kt] = __builtin_amdgcn_mfma_f32_16x16x32_bf16(aq, bk, zero, 0, 0, 0);
        }
        // softmax along keys; row r lives in the 16 lanes of this quad-group.
        // P left UNNORMALIZED (exp(x-max) <= 1, bf16-safe); inv folded into epilogue.
        float inv[4];
        #pragma unroll
        for (int r = 0; r < 4; r++){
            float mx = -1e30f;
            #pragma unroll
            for (int kt = 0; kt < 24; kt++) mx = fmaxf(mx, acc[kt][r]);
            mx = fmaxf(mx, __shfl_xor(mx, 1));
            mx = fmaxf(mx, __shfl_xor(mx, 2));
            mx = fmaxf(mx, __shfl_xor(mx, 4));
            mx = fmaxf(mx, __shfl_xor(mx, 8));
            float sum = 0.f;
            #pragma unroll
            for (int kt = 0; kt < 24; kt++){ acc[kt][r] = __expf(acc[kt][r] - mx); sum += acc[kt][r]; }
            sum += __shfl_xor(sum, 1);
            sum += __shfl_xor(sum, 2);
            sum += __shfl_xor(sum, 4);
            sum += __shfl_xor(sum, 8);
            inv[r] = 1.f / sum;
        }
        float4v oacc[2] = {{0.f,0.f,0.f,0.f},{0.f,0.f,0.f,0.f}};
        // ---- chunk 0: keys 0..191 ----
        #pragma unroll
        for (int kt = 0; kt < 12; kt++)
            #pragma unroll
            for (int r = 0; r < 4; r++)
                Pb[wave][quad*4 + r][kt*16 + l15] = f2bf(acc[kt][r]);
        #pragma unroll
        for (int kk = 0; kk < 6; kk++){
            const short8 ap = *(const short8*)&Pb[wave][l15][kk*32 + quad*8];
            #pragma unroll
            for (int ct = 0; ct < 2; ct++){
                const short8 bv = *(const short8*)&Vt[ct*16 + l15][kk*32 + quad*8];
                oacc[ct] = __builtin_amdgcn_mfma_f32_16x16x32_bf16(ap, bv, oacc[ct], 0, 0, 0);
            }
        }
        // ---- chunk 1: keys 192..383 (reuse Pb; per-wave in-order LDS) ----
        #pragma unroll
        for (int kt = 12; kt < 24; kt++)
            #pragma unroll
            for (int r = 0; r < 4; r++)
                Pb[wave][quad*4 + r][(kt-12)*16 + l15] = f2bf(acc[kt][r]);
        #pragma unroll
        for (int kk = 6; kk < 12; kk++){
            const short8 ap = *(const short8*)&Pb[wave][l15][(kk-6)*32 + quad*8];
            #pragma unroll
            for (int ct = 0; ct < 2; ct++){
                const short8 bv = *(const short8*)&Vt[ct*16 + l15][kk*32 + quad*8];
                oacc[ct] = __builtin_amdgcn_mfma_f32_16x16x32_bf16(ap, bv, oacc[ct], 0, 0, 0);
            }
        }
        // gate + normalize + store (in-place over Q slice; Q for this j-tile consumed)
        #pragma unroll
        for (int ct = 0; ct < 2; ct++){
            const int c = ct*16 + l15;
            #pragma unroll
            for (int r = 0; r < 4; r++){
                const int row = j0 + quad*4 + r;
                const float gv = bf2f(gbase[(long)row*128 + c]);
                obase[(long)row*128 + c] = f2bf(gv * (oacc[ct][r] * inv[r]));
            }
        }
    }
}

// ---------------------------------------------------------------------------
// Kernel 3: out = O' @ Wo^T + bo   [147456x128]@[128x128] -> fp32 d_out
// ---------------------------------------------------------------------------
__global__ __launch_bounds__(256) void k3_outproj(
    const u16* __restrict__ Obuf, const float* __restrict__ Wo, const float* __restrict__ bo,
    float* __restrict__ out)
{
    const int tid = threadIdx.x, lane = tid & 63, wave = tid >> 6;
    const int l15 = lane & 15, quad = lane >> 4;
    const long row0 = (long)blockIdx.x * 64;
    short8 B[2][4];
    #pragma unroll
    for (int g = 0; g < 2; g++){
        const float* bp = Wo + ((wave*2 + g)*16 + l15)*128 + quad*8;
        #pragma unroll
        for (int ks = 0; ks < 4; ks++) B[g][ks] = pack8f(bp + ks*32);
    }
    #pragma unroll
    for (int m = 0; m < 4; m++){
        short8 A[4];
        const u16* ap = Obuf + (row0 + m*16 + l15)*128 + quad*8;
        #pragma unroll
        for (int ks = 0; ks < 4; ks++) A[ks] = *(const short8*)(ap + ks*32);
        #pragma unroll
        for (int g = 0; g < 2; g++){
            float4v c = {0.f,0.f,0.f,0.f};
            #pragma unroll
            for (int ks = 0; ks < 4; ks++)
                c = __builtin_amdgcn_mfma_f32_16x16x32_bf16(A[ks], B[g][ks], c, 0, 0, 0);
            const int n = (wave*2 + g)*16 + l15;
            const float bov = bo[n];
            #pragma unroll
            for (int r = 0; r < 4; r++){
                const long row = row0 + m*16 + quad*4 + r;
                out[row*128 + n] = c[r] + bov;
            }
        }
    }
}

extern "C" void kernel_launch(void* const* d_in, const int* in_sizes, int n_in,
                              void* d_out, int out_size, void* d_ws, size_t ws_size,
                              hipStream_t stream)
{
    (void)in_sizes; (void)n_in; (void)out_size; (void)ws_size;
    const float* z   = (const float*)d_in[0];
    const float* lnw = (const float*)d_in[1];
    const float* lnb = (const float*)d_in[2];
    const float* Wq  = (const float*)d_in[3];
    const float* Wk  = (const float*)d_in[4];
    const float* Wv  = (const float*)d_in[5];
    // d_in[6] = Wb : softmax-invariant (broadcast along key axis) -> unused
    const float* Wg  = (const float*)d_in[7];
    const float* bg  = (const float*)d_in[8];
    const float* Wo  = (const float*)d_in[9];
    const float* bo  = (const float*)d_in[10];

    u16* Qbuf = (u16*)d_ws;                   // 147456*128 bf16 (Q, later O' in-place)
    u16* KV   = Qbuf + 147456L*128;           // 147456*64  bf16 (k | v)
    // ws use: 56,623,104 bytes. G lives in d_out's front half (bf16, consumed
    // by k2 before k3 overwrites d_out with fp32 results).
    u16* Gbuf = (u16*)d_out;                  // 147456*128 bf16 = 37.7MB < 75.5MB

    k1_ln_proj<<<dim3(2304), dim3(256), 0, stream>>>(z, lnw, lnb, Wq, Wk, Wv, Wg, bg,
                                                     Qbuf, KV, Gbuf);
    k2_attn<<<dim3(1536), dim3(256), 0, stream>>>(KV, Gbuf, Qbuf);
    k3_outproj<<<dim3(2304), dim3(256), 0, stream>>>(Qbuf, Wo, bo, (float*)d_out);
}

// Round 3
// 335.897 us; speedup vs baseline: 1.4024x; 1.1971x over previous
//
#include <hip/hip_runtime.h>
#include <math.h>

// TriangleAttention (starting node): B=1, S=384, CZ=128, H=4, CH=32.
// I/O is fp32 (reference dtype); internal compute bf16 MFMA + fp32 softmax/LN.
// Pair bias (Wb) broadcasts along the softmax (key) axis -> softmax-invariant -> skipped.
// MFMA 16x16x32 bf16 layouts (verified m89/m91):
//   A: lane holds A[m=lane&15][k=(lane>>4)*8 + j], j=0..7
//   B: lane holds B[k=(lane>>4)*8 + j][n=lane&15]
//   C/D: col = lane&15, row = (lane>>4)*4 + reg
// R3 change: weights pre-converted to bf16 ONCE (k0a/k0b); k1/k3 compute the
// operand-SWAPPED product D = W . zn^T so each lane's 4 acc regs are 4
// consecutive output channels of ONE row -> packed 8B/16B stores instead of
// scalar 2B/4B stores. Fragment load addresses are unchanged by the swap.

typedef unsigned short u16;
typedef __attribute__((ext_vector_type(8))) short short8;
typedef __attribute__((ext_vector_type(4))) short short4v;
typedef __attribute__((ext_vector_type(4))) float float4v;

union U8 { short8 s; u16 h[8]; };
union U4 { short4v s; u16 h[4]; };

__device__ __forceinline__ float bf2f(u16 x){
    unsigned v = ((unsigned)x) << 16;
    float f; __builtin_memcpy(&f, &v, 4);
    return f;
}
__device__ __forceinline__ u16 f2bf(float f){
    unsigned v; __builtin_memcpy(&v, &f, 4);
    unsigned r = (v + 0x7FFFu + ((v >> 16) & 1u)) >> 16;  // RNE
    return (u16)r;
}
__device__ __forceinline__ short8 pack8f_s(const float* p, float s){
    const float4 a = ((const float4*)p)[0];
    const float4 b = ((const float4*)p)[1];
    U8 u;
    u.h[0]=f2bf(a.x*s); u.h[1]=f2bf(a.y*s); u.h[2]=f2bf(a.z*s); u.h[3]=f2bf(a.w*s);
    u.h[4]=f2bf(b.x*s); u.h[5]=f2bf(b.y*s); u.h[6]=f2bf(b.z*s); u.h[7]=f2bf(b.w*s);
    return u.s;
}

// ---------------------------------------------------------------------------
// k0a: convert {Wq*scale | Wk | Wv | Wg} fp32 -> bf16 into Wbf[320][128].
// Runs before k1. 20 blocks x 256 threads, one short8 per thread.
// ---------------------------------------------------------------------------
__global__ __launch_bounds__(256) void k0a_wconv(
    const float* __restrict__ Wq, const float* __restrict__ Wk,
    const float* __restrict__ Wv, const float* __restrict__ Wg,
    u16* __restrict__ Wbf)
{
    const int i = blockIdx.x * 256 + threadIdx.x;     // [0, 5120)
    const int e = i * 8;                              // element index (row-major 320x128)
    const int n = e >> 7, c0 = e & 127;
    const float* src; float s = 1.f;
    if (n < 128)      { src = Wq + n*128 + c0; s = 0.17677669529663689f; } // fold 1/sqrt(32)
    else if (n < 160) { src = Wk + (n-128)*128 + c0; }
    else if (n < 192) { src = Wv + (n-160)*128 + c0; }
    else              { src = Wg + (n-192)*128 + c0; }
    *(short8*)(Wbf + e) = pack8f_s(src, s);
}

// k0b: Wo fp32 -> bf16 (16384 elems). Runs after k2 (dest overlays dead KV space).
__global__ __launch_bounds__(256) void k0b_wconv(
    const float* __restrict__ Wo, u16* __restrict__ WoBf)
{
    const int e = (blockIdx.x * 256 + threadIdx.x) * 8;   // [0, 16384)
    *(short8*)(WoBf + e) = pack8f_s(Wo + e, 1.f);
}

// ---------------------------------------------------------------------------
// Kernel 1: LayerNorm + fused projection GEMM [64 rows x 320 cols], K=128.
// grid 2304 x 256 threads. Wave w handles n-tiles w*5..w*5+4 over all 64 rows.
// Swapped MFMA: D = Wbf . zn^T, so lane (l15,quad) reg r holds output channel
// nt*16+quad*4+r of row rt*16+l15 -> 8B packed stores.
// ---------------------------------------------------------------------------
__global__ __launch_bounds__(256) void k1_ln_proj(
    const float* __restrict__ z, const float* __restrict__ lnw, const float* __restrict__ lnb,
    const u16* __restrict__ Wbf, const float* __restrict__ bg,
    u16* __restrict__ Qbuf, u16* __restrict__ KVbuf, u16* __restrict__ Gbuf)
{
    __shared__ __align__(16) u16 zn[64][136];   // +8 pad
    const int tid = threadIdx.x;
    const long rowg0 = (long)blockIdx.x * 64;

    {   // LayerNorm: 4 threads per row, 32 elems each, fp32 stats
        const int r = tid >> 2, p = tid & 3;
        const float* src = z + (rowg0 + r) * 128 + p * 32;
        float x[32];
        #pragma unroll
        for (int q = 0; q < 8; q++){
            const float4 v = ((const float4*)src)[q];
            x[q*4+0]=v.x; x[q*4+1]=v.y; x[q*4+2]=v.z; x[q*4+3]=v.w;
        }
        float s = 0.f, ss = 0.f;
        #pragma unroll
        for (int t = 0; t < 32; t++){ s += x[t]; ss += x[t]*x[t]; }
        s += __shfl_xor(s, 1);  ss += __shfl_xor(ss, 1);
        s += __shfl_xor(s, 2);  ss += __shfl_xor(ss, 2);
        const float mean = s * (1.f/128.f);
        const float var  = ss * (1.f/128.f) - mean*mean;
        const float rstd = rsqrtf(var + 1e-5f);
        #pragma unroll
        for (int t = 0; t < 32; t++){
            const int c = p*32 + t;
            zn[r][c] = f2bf((x[t]-mean)*rstd*lnw[c] + lnb[c]);
        }
    }
    __syncthreads();

    const int lane = tid & 63, wave = tid >> 6;
    const int l15 = lane & 15, quad = lane >> 4;

    // zn fragments (B-operand after swap: B[k][row], lane reads zn[l15][quad*8+j])
    short8 ZN[4][4];                      // 4 row-tiles x 4 k-steps
    #pragma unroll
    for (int m = 0; m < 4; m++)
        #pragma unroll
        for (int ks = 0; ks < 4; ks++)
            ZN[m][ks] = *(const short8*)&zn[m*16 + l15][ks*32 + quad*8];

    #pragma unroll
    for (int g = 0; g < 5; g++){
        const int nt = wave*5 + g;        // 0..19 : q(0-7) k(8-9) v(10-11) g(12-19)
        // A-operand: W row (nt*16 + l15), bf16 direct loads
        const u16* wp = Wbf + (nt*16 + l15)*128 + quad*8;
        short8 WF[4];
        #pragma unroll
        for (int ks = 0; ks < 4; ks++) WF[ks] = *(const short8*)(wp + ks*32);
        const int n0 = nt*16 + quad*4;    // 4 consecutive output channels per lane
        #pragma unroll
        for (int m = 0; m < 4; m++){
            float4v c = {0.f,0.f,0.f,0.f};
            #pragma unroll
            for (int ks = 0; ks < 4; ks++)
                c = __builtin_amdgcn_mfma_f32_16x16x32_bf16(WF[ks], ZN[m][ks], c, 0, 0, 0);
            const long row = rowg0 + m*16 + l15;
            if (nt < 8){                                   // Q (scale folded in Wbf)
                U4 u;
                #pragma unroll
                for (int r = 0; r < 4; r++) u.h[r] = f2bf(c[r]);
                *(short4v*)(Qbuf + row*128 + n0) = u.s;
            } else if (nt < 10){                           // K
                U4 u;
                #pragma unroll
                for (int r = 0; r < 4; r++) u.h[r] = f2bf(c[r]);
                *(short4v*)(KVbuf + row*64 + (n0 - 128)) = u.s;
            } else if (nt < 12){                           // V
                U4 u;
                #pragma unroll
                for (int r = 0; r < 4; r++) u.h[r] = f2bf(c[r]);
                *(short4v*)(KVbuf + row*64 + (n0 - 160) + 32) = u.s;
            } else {                                       // G = sigmoid(. + bg)
                const float4 b4 = *(const float4*)&bg[n0 - 192];
                U4 u;
                u.h[0] = f2bf(1.f/(1.f + __expf(-(c[0] + b4.x))));
                u.h[1] = f2bf(1.f/(1.f + __expf(-(c[1] + b4.y))));
                u.h[2] = f2bf(1.f/(1.f + __expf(-(c[2] + b4.z))));
                u.h[3] = f2bf(1.f/(1.f + __expf(-(c[3] + b4.w))));
                *(short4v*)(Gbuf + row*128 + (n0 - 192)) = u.s;
            }
        }
    }
}

// ---------------------------------------------------------------------------
// Kernel 2: attention. One block per (i,h): 384 j-rows x 384 keys, CH=32.
// (unchanged from R2 — 81,408 B LDS -> 2 blocks/CU, chunked Pb reuse,
//  deferred softmax normalization)
// ---------------------------------------------------------------------------
__global__ __launch_bounds__(256, 2) void k2_attn(
    const u16* __restrict__ KVbuf, const u16* __restrict__ Gbuf, u16* __restrict__ QObuf)
{
    __shared__ __align__(16) u16 Ks[384][40];      // K [key][c], +8 pad        30720 B
    __shared__ __align__(16) u16 Vt[32][392];      // V^T [c][key], +8 pad      25088 B
    __shared__ __align__(16) u16 Pb[4][16][200];   // per-wave P half-chunk     25600 B
    const int i = blockIdx.x >> 2, h = blockIdx.x & 3;
    const int tid = threadIdx.x;
    {
        const u16* kvsrc = KVbuf + (long)i * 384 * 64;
        for (int idx = tid; idx < 384*8; idx += 256){
            const int k = idx >> 3, c8 = idx & 7;
            U8 d; d.s = *(const short8*)(kvsrc + k*64 + c8*8);
            if (c8 < 4) *(short8*)&Ks[k][c8*8] = d.s;
            else {
                const int c0 = (c8 - 4) * 8;
                #pragma unroll
                for (int jj = 0; jj < 8; jj++) Vt[c0 + jj][k] = d.h[jj];
            }
        }
    }
    __syncthreads();

    const int lane = tid & 63, wave = tid >> 6;
    const int l15 = lane & 15, quad = lane >> 4;
    const u16* qbase = QObuf + (long)i * 384 * 128 + h * 32;
    const u16* gbase = Gbuf  + (long)i * 384 * 128 + h * 32;
    u16* obase = QObuf + (long)i * 384 * 128 + h * 32;

    for (int t = 0; t < 6; t++){
        const int j0 = (wave*6 + t) * 16;
        const short8 aq = *(const short8*)(qbase + (long)(j0 + l15)*128 + quad*8);
        float4v acc[24];
        #pragma unroll
        for (int kt = 0; kt < 24; kt++){
            const short8 bk = *(const short8*)&Ks[kt*16 + l15][quad*8];
            float4v zero = {0.f,0.f,0.f,0.f};
            acc[kt] = __builtin_amdgcn_mfma_f32_16x16x32_bf16(aq, bk, zero, 0, 0, 0);
        }
        float inv[4];
        #pragma unroll
        for (int r = 0; r < 4; r++){
            float mx = -1e30f;
            #pragma unroll
            for (int kt = 0; kt < 24; kt++) mx = fmaxf(mx, acc[kt][r]);
            mx = fmaxf(mx, __shfl_xor(mx, 1));
            mx = fmaxf(mx, __shfl_xor(mx, 2));
            mx = fmaxf(mx, __shfl_xor(mx, 4));
            mx = fmaxf(mx, __shfl_xor(mx, 8));
            float sum = 0.f;
            #pragma unroll
            for (int kt = 0; kt < 24; kt++){ acc[kt][r] = __expf(acc[kt][r] - mx); sum += acc[kt][r]; }
            sum += __shfl_xor(sum, 1);
            sum += __shfl_xor(sum, 2);
            sum += __shfl_xor(sum, 4);
            sum += __shfl_xor(sum, 8);
            inv[r] = 1.f / sum;
        }
        float4v oacc[2] = {{0.f,0.f,0.f,0.f},{0.f,0.f,0.f,0.f}};
        #pragma unroll
        for (int kt = 0; kt < 12; kt++)
            #pragma unroll
            for (int r = 0; r < 4; r++)
                Pb[wave][quad*4 + r][kt*16 + l15] = f2bf(acc[kt][r]);
        #pragma unroll
        for (int kk = 0; kk < 6; kk++){
            const short8 ap = *(const short8*)&Pb[wave][l15][kk*32 + quad*8];
            #pragma unroll
            for (int ct = 0; ct < 2; ct++){
                const short8 bv = *(const short8*)&Vt[ct*16 + l15][kk*32 + quad*8];
                oacc[ct] = __builtin_amdgcn_mfma_f32_16x16x32_bf16(ap, bv, oacc[ct], 0, 0, 0);
            }
        }
        #pragma unroll
        for (int kt = 12; kt < 24; kt++)
            #pragma unroll
            for (int r = 0; r < 4; r++)
                Pb[wave][quad*4 + r][(kt-12)*16 + l15] = f2bf(acc[kt][r]);
        #pragma unroll
        for (int kk = 6; kk < 12; kk++){
            const short8 ap = *(const short8*)&Pb[wave][l15][(kk-6)*32 + quad*8];
            #pragma unroll
            for (int ct = 0; ct < 2; ct++){
                const short8 bv = *(const short8*)&Vt[ct*16 + l15][kk*32 + quad*8];
                oacc[ct] = __builtin_amdgcn_mfma_f32_16x16x32_bf16(ap, bv, oacc[ct], 0, 0, 0);
            }
        }
        #pragma unroll
        for (int ct = 0; ct < 2; ct++){
            const int c = ct*16 + l15;
            #pragma unroll
            for (int r = 0; r < 4; r++){
                const int row = j0 + quad*4 + r;
                const float gv = bf2f(gbase[(long)row*128 + c]);
                obase[(long)row*128 + c] = f2bf(gv * (oacc[ct][r] * inv[r]));
            }
        }
    }
}

// ---------------------------------------------------------------------------
// Kernel 3: out = O' @ Wo^T + bo   [147456x128]@[128x128] -> fp32 d_out
// Swapped MFMA (D = Wo . O'^T): lane holds 4 consecutive n for one row ->
// one float4 store per (g, row-tile). Wo pre-converted bf16 (k0b).
// ---------------------------------------------------------------------------
__global__ __launch_bounds__(256) void k3_outproj(
    const u16* __restrict__ Obuf, const u16* __restrict__ WoBf, const float* __restrict__ bo,
    float* __restrict__ out)
{
    const int tid = threadIdx.x, lane = tid & 63, wave = tid >> 6;
    const int l15 = lane & 15, quad = lane >> 4;
    const long row0 = (long)blockIdx.x * 64;
    short8 WF[2][4];
    #pragma unroll
    for (int g = 0; g < 2; g++){
        const u16* wp = WoBf + ((wave*2 + g)*16 + l15)*128 + quad*8;
        #pragma unroll
        for (int ks = 0; ks < 4; ks++) WF[g][ks] = *(const short8*)(wp + ks*32);
    }
    #pragma unroll
    for (int m = 0; m < 4; m++){
        short8 OF[4];
        const u16* ap = Obuf + (row0 + m*16 + l15)*128 + quad*8;
        #pragma unroll
        for (int ks = 0; ks < 4; ks++) OF[ks] = *(const short8*)(ap + ks*32);
        #pragma unroll
        for (int g = 0; g < 2; g++){
            float4v c = {0.f,0.f,0.f,0.f};
            #pragma unroll
            for (int ks = 0; ks < 4; ks++)
                c = __builtin_amdgcn_mfma_f32_16x16x32_bf16(WF[g][ks], OF[ks], c, 0, 0, 0);
            const int n0 = (wave*2 + g)*16 + quad*4;
            const float4 b4 = *(const float4*)&bo[n0];
            const long row = row0 + m*16 + l15;
            float4 o4;
            o4.x = c[0] + b4.x; o4.y = c[1] + b4.y;
            o4.z = c[2] + b4.z; o4.w = c[3] + b4.w;
            *(float4*)(out + row*128 + n0) = o4;
        }
    }
}

extern "C" void kernel_launch(void* const* d_in, const int* in_sizes, int n_in,
                              void* d_out, int out_size, void* d_ws, size_t ws_size,
                              hipStream_t stream)
{
    (void)in_sizes; (void)n_in; (void)out_size; (void)ws_size;
    const float* z   = (const float*)d_in[0];
    const float* lnw = (const float*)d_in[1];
    const float* lnb = (const float*)d_in[2];
    const float* Wq  = (const float*)d_in[3];
    const float* Wk  = (const float*)d_in[4];
    const float* Wv  = (const float*)d_in[5];
    // d_in[6] = Wb : softmax-invariant (broadcast along key axis) -> unused
    const float* Wg  = (const float*)d_in[7];
    const float* bg  = (const float*)d_in[8];
    const float* Wo  = (const float*)d_in[9];
    const float* bo  = (const float*)d_in[10];

    u16* Qbuf = (u16*)d_ws;                   // 147456*128 bf16 (Q, later O' in-place)
    u16* KV   = Qbuf + 147456L*128;           // 147456*64  bf16 (k | v)
    // G lives in d_out's front half (bf16, consumed by k2 before k3 overwrites
    // d_out with fp32 results). Wbf (320x128 bf16 = 80KB) lives right after G
    // in d_out — consumed by k1, overwritten later by k3's fp32 output.
    u16* Gbuf = (u16*)d_out;                  // 147456*128 bf16 = 37.7MB < 75.5MB
    u16* Wbf  = Gbuf + 147456L*128;           // 40960 u16 = 80KB
    // WoBf overlays the (dead-after-k2) front of the KV region.
    u16* WoBf = KV;                           // 16384 u16 = 32KB

    k0a_wconv<<<dim3(20), dim3(256), 0, stream>>>(Wq, Wk, Wv, Wg, Wbf);
    k1_ln_proj<<<dim3(2304), dim3(256), 0, stream>>>(z, lnw, lnb, Wbf, bg,
                                                     Qbuf, KV, Gbuf);
    k2_attn<<<dim3(1536), dim3(256), 0, stream>>>(KV, Gbuf, Qbuf);
    k0b_wconv<<<dim3(8), dim3(256), 0, stream>>>(Wo, WoBf);
    k3_outproj<<<dim3(2304), dim3(256), 0, stream>>>(Qbuf, WoBf, bo, (float*)d_out);
}